// Round 13
// baseline (8614.381 us; speedup 1.0000x reference)
//
#include <hip/hip_runtime.h>
#include <math.h>

#define BEAM   10
#define MAXLEN 32
#define SLEN   32
#define HD     500
#define ED     500
#define G4     2000
#define PV     50000
#define NEGF   (-1e30f)
#define NEGD   (-1.0e30)

#define NSTRIP 196               // logits strip blocks (196*256 >= 50000)
#define CPR    (NSTRIP * BEAM)   // 1960 candidates per row

typedef unsigned long long u64;

// ---------------- ws layout (float element offsets) ----------------
#define OFF_X      0
#define OFF_CBUF   64000
#define OFF_GBUF   65000
#define OFF_CTX    69000
#define OFF_DH     85000
#define OFF_DC     90000
#define OFF_DG     95000
#define OFF_H2     115000
#define OFF_C2     120000
#define OFF_O      125000
#define OFF_SCD    135000   // double[20] score ping-pong
#define OFF_TOK    135040
#define OFF_PREVK  135060
#define OFF_NEXTY  135380
// fallback-path regions (R4 layout)
#define OFF_PARTF  136000   // double[7820]
#define OFF_CANDF  152000   // u64[3200]
#define OFF_LOG    160000   // fallback logits buffer
// new-path regions (inside fallback LOG region; paths exclusive)
#define OFF_PARTD  160284   // double[1960]
#define OFF_CAND   165604   // u64[19600]
#define OFF_OWT    660000   // float4-blocked transposed out_W (100 MB)
#define NEED_T_BYTES ((size_t)(OFF_OWT + (size_t)HD * PV) * 4)

__device__ __forceinline__ float sigf(float x) { return 1.f / (1.f + expf(-x)); }

__device__ __forceinline__ unsigned fkey(float f) {
    unsigned u = __float_as_uint(f);
    return (u & 0x80000000u) ? ~u : (u | 0x80000000u);
}
__device__ __forceinline__ float unfkey(unsigned k) {
    unsigned u = (k & 0x80000000u) ? (k & 0x7fffffffu) : ~k;
    return __uint_as_float(u);
}

// ---------------- prep ----------------
__global__ void k_prep(const int* __restrict__ g_seq, const float* __restrict__ enc_emb,
                       const float* __restrict__ Wih, const float* __restrict__ bih,
                       const float* __restrict__ bhh, float* __restrict__ X,
                       float* __restrict__ cbuf0) {
    if (blockIdx.x == 0) {
        for (int j = threadIdx.x; j < HD; j += 256) cbuf0[j] = 0.f;
    }
    int wv = (blockIdx.x * blockDim.x + threadIdx.x) >> 6;
    int lane = threadIdx.x & 63;
    if (wv >= SLEN * G4) return;
    int t = wv / G4, r = wv - t * G4;
    const float* emb = enc_emb + (size_t)g_seq[t] * ED;
    const float* w = Wih + (size_t)r * ED;
    float acc = 0.f;
    for (int ki = 0; ki < 8; ki++) { int k = ki * 64 + lane; if (k < ED) acc += emb[k] * w[k]; }
    for (int o = 32; o; o >>= 1) acc += __shfl_down(acc, o);
    if (lane == 0) X[t * G4 + r] = acc + bih[r] + bhh[r];
}

// ---------------- out_W blocked transpose ----------------
__global__ void k_transpose4(const float* __restrict__ outW, float* __restrict__ outW4) {
    __shared__ float t_lds[64][65];
    int tid = threadIdx.x;
    int pbase = blockIdx.x * 64, kbase = blockIdx.y * 64;
    for (int e = 0; e < 16; e++) {
        int idx = e * 256 + tid; int pl = idx >> 6, kl = idx & 63;
        int pp = pbase + pl, kk = kbase + kl;
        t_lds[pl][kl] = (pp < PV && kk < HD) ? outW[(size_t)pp * HD + kk] : 0.f;
    }
    __syncthreads();
    for (int e = 0; e < 4; e++) {
        int idx = e * 256 + tid;
        int pl = idx & 63, kb = idx >> 6;
        int pp = pbase + pl;
        int kglob = kbase + kb * 4;
        if (pp < PV && kglob < HD) {
            float4 v;
            v.x = t_lds[pl][kb * 4 + 0];
            v.y = t_lds[pl][kb * 4 + 1];
            v.z = t_lds[pl][kb * 4 + 2];
            v.w = t_lds[pl][kb * 4 + 3];
            *(float4*)(outW4 + ((size_t)(kbase / 4 + kb) * PV + pp) * 4) = v;
        }
    }
}

// ---------------- encoder step (R4-validated) ----------------
__global__ void k_enc(const float* __restrict__ Whh, const float* __restrict__ X,
                      float* __restrict__ gbuf, float* __restrict__ cbuf,
                      float* __restrict__ context, float* __restrict__ dec_h,
                      float* __restrict__ dec_c, double* __restrict__ scores,
                      int* __restrict__ tokens, int t) {
    __shared__ float h_lds[HD];
    const float* gprev = gbuf + ((t + 1) & 1) * G4;
    float*       gcur  = gbuf + (t & 1) * G4;
    const float* cprev = cbuf + ((t + 1) & 1) * HD;
    float*       ccur  = cbuf + (t & 1) * HD;
    int tid = threadIdx.x;
    if (t > 0) {
        for (int j = tid; j < HD; j += 256) {
            float gi = gprev[j], gf = gprev[HD + j], gg = gprev[2 * HD + j], go = gprev[3 * HD + j];
            float c = sigf(gf) * cprev[j] + sigf(gi) * tanhf(gg);
            float h = sigf(go) * tanhf(c);
            h_lds[j] = h;
            if (blockIdx.x == 0) {
                ccur[j] = c;
                context[(t - 1) * HD + j] = h;
                if (t == SLEN) {
                    for (int b = 0; b < BEAM; b++) { dec_h[b * HD + j] = h; dec_c[b * HD + j] = c; }
                }
            }
        }
    } else {
        for (int j = tid; j < HD; j += 256) h_lds[j] = 0.f;
    }
    if (t == SLEN && blockIdx.x == 0 && tid == 0) {
        for (int b = 0; b < BEAM; b++) scores[b] = 0.0;
        tokens[0] = 2; for (int b = 1; b < BEAM; b++) tokens[b] = 1;
    }
    __syncthreads();
    if (t < SLEN) {
        int wv = blockIdx.x * 4 + (tid >> 6), lane = tid & 63;
        for (int r = wv; r < G4; r += 1000) {
            const float* w = Whh + (size_t)r * HD;
            float acc = 0.f;
            for (int ki = 0; ki < 8; ki++) { int k = ki * 64 + lane; if (k < HD) acc += h_lds[k] * w[k]; }
            for (int o = 32; o; o >>= 1) acc += __shfl_down(acc, o);
            if (lane == 0) gcur[r] = X[t * G4 + r] + acc;
        }
    }
}

// ================= redundant merge (device fn, 512 threads) =================
struct MrgSm {
    double lse[BEAM]; double scl[BEAM];
    u64 rc[BEAM * BEAM];
    double gbv[8]; unsigned gbf[8]; unsigned winf;
    int pk[BEAM]; int ny[BEAM]; double val[BEAM];
};

__device__ __forceinline__ void do_merge(MrgSm* M, const double* __restrict__ part,
                                         const u64* __restrict__ cand,
                                         const double* __restrict__ sc_in,
                                         int m, int tid) {
    int wv = tid >> 6, lane = tid & 63;
    if (tid < BEAM) M->scl[tid] = sc_in[tid];
    // per-row lse (fp64)
    for (int r = wv; r < BEAM; r += 8) {
        double s = 0.0;
        for (int i = lane; i < NSTRIP; i += 64) s += part[r * NSTRIP + i];
        for (int o = 32; o; o >>= 1) s += __shfl_down(s, o);
        if (lane == 0) M->lse[r] = log(s);
    }
    // per-row top-10 over 1960 strip candidates; STATIC indexing (rule #20)
    for (int r = wv; r < BEAM; r += 8) {
        u64 kk[31];
#pragma unroll
        for (int e = 0; e < 31; e++) {
            int i = lane + e * 64;
            kk[e] = (i < CPR) ? cand[(size_t)r * CPR + i] : 0ull;
        }
        for (int round = 0; round < BEAM; ++round) {
            u64 mx = 0ull;
#pragma unroll
            for (int e = 0; e < 31; e++) if (kk[e] > mx) mx = kk[e];
            for (int o = 32; o; o >>= 1) { u64 t2 = __shfl_down(mx, o); if (t2 > mx) mx = t2; }
            u64 win = __shfl(mx, 0);
#pragma unroll
            for (int e = 0; e < 31; e++) if (kk[e] == win) kk[e] = 0ull;
            if (lane == 0) M->rc[r * BEAM + round] = win;
        }
    }
    __syncthreads();
    // global merge over 100 candidates (fp64 value, flat-index tiebreak)
    double cv = -1.0e308; unsigned cf = 0xFFFFFFFFu;
    if (tid < BEAM * BEAM) {
        u64 k0 = M->rc[tid];
        if (k0) {
            int r2 = tid / BEAM;
            float v = unfkey((unsigned)(k0 >> 32));
            unsigned p = ~((unsigned)k0);
            double v2;
            if (m == 0) v2 = (r2 == 0) ? ((double)v - M->lse[0]) : NEGD;
            else        v2 = ((double)v - M->lse[r2]) + M->scl[r2];
            cv = v2; cf = (unsigned)r2 * PV + p;
        }
    }
    for (int round = 0; round < BEAM; ++round) {
        double bv = cv; unsigned bf = cf;
        for (int o = 32; o; o >>= 1) {
            double ov = __shfl_down(bv, o);
            unsigned of = __shfl_down(bf, o);
            if (ov > bv || (ov == bv && of < bf)) { bv = ov; bf = of; }
        }
        if (lane == 0) { M->gbv[wv] = bv; M->gbf[wv] = bf; }
        __syncthreads();
        if (tid == 0) {
            double xv = M->gbv[0]; unsigned xf = M->gbf[0];
            for (int i = 1; i < 8; i++) {
                if (M->gbv[i] > xv || (M->gbv[i] == xv && M->gbf[i] < xf)) { xv = M->gbv[i]; xf = M->gbf[i]; }
            }
            M->winf = xf;
            int pk = (int)(xf / PV);
            int ny = (int)(xf - (unsigned)pk * PV);
            M->pk[round] = pk; M->ny[round] = ny; M->val[round] = xv;
        }
        __syncthreads();
        if (cf == M->winf) { cv = -1.0e308; cf = 0xFFFFFFFFu; }
        __syncthreads();
    }
}

// ================= fused merge(t-1) + gates (125 x 512) =================
__global__ __launch_bounds__(512) void k_gates_m(
        const float* __restrict__ decEmb, const float* __restrict__ Wih,
        const float* __restrict__ Whh, const float* __restrict__ bih,
        const float* __restrict__ bhh,
        const double* __restrict__ part, const u64* __restrict__ cand,
        const double* __restrict__ sc_in, double* __restrict__ sc_out,
        const float* __restrict__ h2w, const float* __restrict__ c2w,
        float* __restrict__ dc, const float* __restrict__ dh0,
        int* __restrict__ prevK, int* __restrict__ nextY,
        float* __restrict__ gates, int t) {
    __shared__ float e_lds[BEAM * ED];
    __shared__ float h_lds[BEAM * HD];
    __shared__ MrgSm M;
    int tid = threadIdx.x, bid = blockIdx.x;
    int wv = tid >> 6, lane = tid & 63;

    if (t > 0) {
        int m = t - 1;
        do_merge(&M, part, cand, sc_in, m, tid);
        if (tid < BEAM && bid == 0) {
            sc_out[tid] = M.val[tid];
            prevK[m * BEAM + tid] = M.pk[tid];
            nextY[m * BEAM + tid] = M.ny[tid];
        }
        __syncthreads();
        for (int idx = tid; idx < BEAM * HD; idx += 512) {
            int b = idx / HD, j = idx - b * HD;
            h_lds[idx] = h2w[M.pk[b] * HD + j];
            e_lds[idx] = decEmb[(size_t)M.ny[b] * ED + j];
            if (bid == 0) dc[idx] = c2w[M.pk[b] * HD + j];
        }
    } else {
        for (int idx = tid; idx < BEAM * HD; idx += 512) {
            int b = idx / HD, j = idx - b * HD;
            int tk = (b == 0) ? 2 : 1;
            h_lds[idx] = dh0[idx];
            e_lds[idx] = decEmb[(size_t)tk * ED + j];
        }
    }
    __syncthreads();

    // gates: 16 rows/block, 2 rows/wave (per-row math identical to R4 k_gates)
    for (int rr = 0; rr < 2; ++rr) {
        int r = bid * 16 + wv * 2 + rr;
        const float* wi = Wih + (size_t)r * ED;
        const float* wh = Whh + (size_t)r * HD;
        float acc[BEAM];
#pragma unroll
        for (int b = 0; b < BEAM; b++) acc[b] = 0.f;
        for (int ki = 0; ki < 8; ki++) {
            int k = ki * 64 + lane;
            if (k < ED) {
                float w = wi[k];
#pragma unroll
                for (int b = 0; b < BEAM; b++) acc[b] += w * e_lds[b * ED + k];
            }
        }
        for (int ki = 0; ki < 8; ki++) {
            int k = ki * 64 + lane;
            if (k < HD) {
                float w = wh[k];
#pragma unroll
                for (int b = 0; b < BEAM; b++) acc[b] += w * h_lds[b * HD + k];
            }
        }
#pragma unroll
        for (int b = 0; b < BEAM; b++) {
            float v = acc[b];
            for (int o = 32; o; o >>= 1) v += __shfl_down(v, o);
            acc[b] = v;
        }
        if (lane == 0) {
            float bb = bih[r] + bhh[r];
#pragma unroll
            for (int b = 0; b < BEAM; b++) gates[b * G4 + r] = acc[b] + bb;
        }
    }
}

// ================= fused attn + oproj + logits + strip top-10 (196 x 1024) =================
// Each block REDUNDANTLY computes pointwise-LSTM/attention/oproj (deterministic,
// bit-identical across blocks: same code, same inputs), then its own logits strip.
// Per-dot reduction orders identical to the R12-validated kernels.
__global__ __launch_bounds__(1024) void k_fused(
        const float* __restrict__ gates, const float* __restrict__ c_ws,
        const float* __restrict__ context, const float* __restrict__ attnW,
        float* __restrict__ h2_ws, float* __restrict__ c2_ws,
        const float* __restrict__ outW4, const float* __restrict__ outB,
        u64* __restrict__ cand, double* __restrict__ part) {
    __shared__ __align__(16) char sm[62560];
    float* h2_lds   = (float*)sm;                 // [0,20000)
    float* wctx_lds = (float*)(sm + 20000);       // [20000,40000)
    float* s_lds    = (float*)(sm + 40000);       // [40000,41280)
    float* a_lds    = (float*)(sm + 41280);       // [41280,42560)
    float* o_lds    = (float*)(sm + 42560);       // [42560,62560)
    int tid = threadIdx.x, bid = blockIdx.x;
    int wv = tid >> 6, lane = tid & 63;

    // Phase A: pointwise LSTM (block 0 persists h2/c2 for next merge)
    for (int idx = tid; idx < BEAM * HD; idx += 1024) {
        int b = idx / HD, j = idx - b * HD;
        float gi = gates[b * G4 + j], gf = gates[b * G4 + HD + j];
        float gg = gates[b * G4 + 2 * HD + j], go = gates[b * G4 + 3 * HD + j];
        float c = sigf(gf) * c_ws[idx] + sigf(gi) * tanhf(gg);
        float h2 = sigf(go) * tanhf(c);
        h2_lds[idx] = h2;
        if (bid == 0) { c2_ws[idx] = c; h2_ws[idx] = h2; }
    }
    __syncthreads();

    // Phase B: scores (16 waves, 2 s each; per-dot order identical to validated)
    for (int si = 0; si < 2; ++si) {
        int s = wv + 16 * si;
        float acc[BEAM];
#pragma unroll
        for (int b = 0; b < BEAM; b++) acc[b] = 0.f;
        for (int ki = 0; ki < 8; ki++) {
            int k = ki * 64 + lane;
            if (k < HD) {
                float c = context[s * HD + k];
#pragma unroll
                for (int b = 0; b < BEAM; b++) acc[b] += c * h2_lds[b * HD + k];
            }
        }
#pragma unroll
        for (int b = 0; b < BEAM; b++) {
            float v = acc[b];
            for (int o = 32; o; o >>= 1) v += __shfl_down(v, o);
            if (lane == 0) s_lds[b * SLEN + s] = v;
        }
    }
    __syncthreads();

    // Phase B2: softmax (wave 0; identical to validated)
    if (wv == 0) {
        for (int b = 0; b < BEAM; ++b) {
            float v = (lane < SLEN) ? s_lds[b * SLEN + lane] : -INFINITY;
            float m = v;
            for (int o = 32; o; o >>= 1) m = fmaxf(m, __shfl_xor(m, o));
            float e = (lane < SLEN) ? expf(v - m) : 0.f;
            float sum = e;
            for (int o = 32; o; o >>= 1) sum += __shfl_xor(sum, o);
            if (lane < SLEN) a_lds[b * SLEN + lane] = e / sum;
        }
    }
    __syncthreads();

    // Phase C: wctx (thread owns j; per-(b,j) sum order identical to validated)
    if (tid < HD) {
        float w0[BEAM];
#pragma unroll
        for (int b = 0; b < BEAM; b++) w0[b] = 0.f;
        for (int s = 0; s < SLEN; ++s) {
            float c0 = context[s * HD + tid];
#pragma unroll
            for (int b = 0; b < BEAM; b++) w0[b] += a_lds[b * SLEN + s] * c0;
        }
#pragma unroll
        for (int b = 0; b < BEAM; b++) wctx_lds[b * HD + tid] = w0[b];
    }
    __syncthreads();

    // Phase D: oproj for ALL 500 j (wave per j; per-dot order identical to validated)
    for (int jj = 0; jj < 32; ++jj) {
        int j = wv + 16 * jj;
        if (j < HD) {
            const float* w = attnW + (size_t)j * 1000;
            float acc[BEAM];
#pragma unroll
            for (int b = 0; b < BEAM; b++) acc[b] = 0.f;
            for (int ki = 0; ki < 16; ki++) {
                int k = ki * 64 + lane;
                if (k < 1000) {
                    float wk = w[k];
#pragma unroll
                    for (int b = 0; b < BEAM; b++) {
                        float h = (k < HD) ? h2_lds[b * HD + k] : wctx_lds[b * HD + k - HD];
                        acc[b] += wk * h;
                    }
                }
            }
#pragma unroll
            for (int b = 0; b < BEAM; b++) {
                float v = acc[b];
                for (int o = 32; o; o >>= 1) v += __shfl_down(v, o);
                acc[b] = v;
            }
            if (lane == 0) {
#pragma unroll
                for (int b = 0; b < BEAM; b++) o_lds[b * HD + j] = tanhf(acc[b]);
            }
        }
    }
    __syncthreads();

    // Phase E: logits (R12 4-way K-split association) + fp64 sumexp + strip top-10
    float* pt = (float*)sm;   // reuse [0,40960): h2/wctx/s/a all dead
    int col = tid & 255, kc = tid >> 8;
    int p = bid * 256 + col;
    bool valid = (p < PV);
    int pc = valid ? p : (PV - 1);
    {
        float acc[BEAM];
#pragma unroll
        for (int b = 0; b < BEAM; b++) acc[b] = 0.f;
        int kb0 = kc * 32, kb1 = (kc == 3) ? 125 : (kb0 + 32);
        const float4* wp = (const float4*)outW4;
        const float4* o4 = (const float4*)o_lds;
        for (int kb = kb0; kb < kb1; ++kb) {
            float4 w = wp[(size_t)kb * PV + pc];
#pragma unroll
            for (int b = 0; b < BEAM; b++) {
                float4 o = o4[b * 125 + kb];
                acc[b] += w.x * o.x + w.y * o.y + w.z * o.z + w.w * o.w;
            }
        }
#pragma unroll
        for (int b = 0; b < BEAM; b++) pt[(kc * 256 + col) * BEAM + b] = acc[b];
    }
    __syncthreads();
    float lg[BEAM];
    if (tid < 256) {
        float ob = outB[pc];
#pragma unroll
        for (int b = 0; b < BEAM; b++)
            lg[b] = pt[(0 * 256 + tid) * BEAM + b] + pt[(1 * 256 + tid) * BEAM + b]
                  + pt[(2 * 256 + tid) * BEAM + b] + pt[(3 * 256 + tid) * BEAM + b] + ob;
    }
    __syncthreads();   // all pt reads done
    double* pd = (double*)sm;            // [0,20480)
    u64*    kl = (u64*)(sm + 20480);     // [20480,40960)
    if (tid < 256) {
#pragma unroll
        for (int b = 0; b < BEAM; b++) {
            pd[b * 256 + tid] = valid ? exp((double)lg[b]) : 0.0;
            kl[b * 256 + tid] = valid ? (((u64)fkey(lg[b]) << 32) | (unsigned)(~(unsigned)p)) : 0ull;
        }
    }
    __syncthreads();
    if (wv < BEAM) {
        int r = wv;
        double s = pd[r * 256 + lane] + pd[r * 256 + 64 + lane]
                 + pd[r * 256 + 128 + lane] + pd[r * 256 + 192 + lane];
        for (int o = 32; o; o >>= 1) s += __shfl_down(s, o);
        if (lane == 0) part[r * NSTRIP + bid] = s;
        u64 kk[4];
#pragma unroll
        for (int j = 0; j < 4; j++) kk[j] = kl[r * 256 + j * 64 + lane];
        for (int round = 0; round < BEAM; round++) {
            u64 m = kk[0];
            if (kk[1] > m) m = kk[1];
            if (kk[2] > m) m = kk[2];
            if (kk[3] > m) m = kk[3];
            for (int o = 32; o; o >>= 1) {
                u64 t2 = __shfl_down(m, o);
                if (t2 > m) m = t2;
            }
            u64 win = __shfl(m, 0);
#pragma unroll
            for (int j = 0; j < 4; j++) if (kk[j] == win) kk[j] = 0ull;
            if (lane == 0) cand[(size_t)r * CPR + bid * 10 + round] = win;
        }
    }
}

// ---------------- final merge(31) + traceback (1 x 512) ----------------
__global__ __launch_bounds__(512) void k_final(
        const double* __restrict__ part, const u64* __restrict__ cand,
        const double* __restrict__ sc_in,
        int* __restrict__ prevK, int* __restrict__ nextY, int* __restrict__ out) {
    __shared__ MrgSm M;
    int tid = threadIdx.x;
    do_merge(&M, part, cand, sc_in, MAXLEN - 1, tid);
    if (tid < BEAM) {
        prevK[(MAXLEN - 1) * BEAM + tid] = M.pk[tid];
        nextY[(MAXLEN - 1) * BEAM + tid] = M.ny[tid];
    }
    __syncthreads();
    if (tid < BEAM) {
        int cur = tid;
        for (int tt = MAXLEN - 1; tt >= 0; tt--) {
            out[tid * MAXLEN + tt] = nextY[tt * BEAM + cur];
            cur = prevK[tt * BEAM + cur];
        }
    }
}

// ======================================================================
// R4 fallback kernels (used only when ws is too small for transposed W)
// ======================================================================
__global__ __launch_bounds__(1024) void k_gates(
        const float* __restrict__ dec_emb, const float* __restrict__ Wih,
        const float* __restrict__ Whh, const float* __restrict__ bih,
        const float* __restrict__ bhh, const int* __restrict__ tokens,
        const float* __restrict__ h_ws, float* __restrict__ gates) {
    __shared__ float e_lds[BEAM * ED];
    __shared__ float h_lds[BEAM * HD];
    int tid = threadIdx.x;
    for (int idx = tid; idx < BEAM * ED; idx += 1024) {
        int b = idx / ED, k = idx - b * ED;
        e_lds[idx] = dec_emb[(size_t)tokens[b] * ED + k];
        h_lds[idx] = h_ws[idx];
    }
    __syncthreads();
    int wv = tid >> 6, lane = tid & 63;
    int r = blockIdx.x * 16 + wv;
    const float* wi = Wih + (size_t)r * ED;
    const float* wh = Whh + (size_t)r * HD;
    float acc[BEAM];
#pragma unroll
    for (int b = 0; b < BEAM; b++) acc[b] = 0.f;
    for (int ki = 0; ki < 8; ki++) {
        int k = ki * 64 + lane;
        if (k < ED) {
            float w = wi[k];
#pragma unroll
            for (int b = 0; b < BEAM; b++) acc[b] += w * e_lds[b * ED + k];
        }
    }
    for (int ki = 0; ki < 8; ki++) {
        int k = ki * 64 + lane;
        if (k < HD) {
            float w = wh[k];
#pragma unroll
            for (int b = 0; b < BEAM; b++) acc[b] += w * h_lds[b * HD + k];
        }
    }
#pragma unroll
    for (int b = 0; b < BEAM; b++) {
        float v = acc[b];
        for (int o = 32; o; o >>= 1) v += __shfl_down(v, o);
        acc[b] = v;
    }
    if (lane == 0) {
        float bb = bih[r] + bhh[r];
#pragma unroll
        for (int b = 0; b < BEAM; b++) gates[b * G4 + r] = acc[b] + bb;
    }
}

__global__ __launch_bounds__(256) void k_attn_oproj(
        const float* __restrict__ gates, const float* __restrict__ c_ws,
        const float* __restrict__ context, const float* __restrict__ attnW,
        float* __restrict__ h2_ws, float* __restrict__ c2_ws, float* __restrict__ o_ws) {
    __shared__ float h2_lds[BEAM * HD];
    __shared__ float wctx_lds[BEAM * HD];
    __shared__ float s_lds[BEAM * SLEN];
    __shared__ float a_lds[BEAM * SLEN];
    int tid = threadIdx.x;
    int wv = tid >> 6, lane = tid & 63;
    for (int idx = tid; idx < BEAM * HD; idx += 256) {
        int b = idx / HD, j = idx - b * HD;
        float gi = gates[b * G4 + j], gf = gates[b * G4 + HD + j];
        float gg = gates[b * G4 + 2 * HD + j], go = gates[b * G4 + 3 * HD + j];
        float c = sigf(gf) * c_ws[idx] + sigf(gi) * tanhf(gg);
        float h2 = sigf(go) * tanhf(c);
        h2_lds[idx] = h2;
        if (blockIdx.x == 0) { c2_ws[idx] = c; h2_ws[idx] = h2; }
    }
    __syncthreads();
    for (int si = 0; si < 8; ++si) {
        int s = wv + 4 * si;
        float acc[BEAM];
#pragma unroll
        for (int b = 0; b < BEAM; b++) acc[b] = 0.f;
        for (int ki = 0; ki < 8; ki++) {
            int k = ki * 64 + lane;
            if (k < HD) {
                float c = context[s * HD + k];
#pragma unroll
                for (int b = 0; b < BEAM; b++) acc[b] += c * h2_lds[b * HD + k];
            }
        }
#pragma unroll
        for (int b = 0; b < BEAM; b++) {
            float v = acc[b];
            for (int o = 32; o; o >>= 1) v += __shfl_down(v, o);
            if (lane == 0) s_lds[b * SLEN + s] = v;
        }
    }
    __syncthreads();
    if (wv == 0) {
        for (int b = 0; b < BEAM; ++b) {
            float v = (lane < SLEN) ? s_lds[b * SLEN + lane] : -INFINITY;
            float m = v;
            for (int o = 32; o; o >>= 1) m = fmaxf(m, __shfl_xor(m, o));
            float e = (lane < SLEN) ? expf(v - m) : 0.f;
            float sum = e;
            for (int o = 32; o; o >>= 1) sum += __shfl_xor(sum, o);
            if (lane < SLEN) a_lds[b * SLEN + lane] = e / sum;
        }
    }
    __syncthreads();
    {
        float w0[BEAM], w1[BEAM];
#pragma unroll
        for (int b = 0; b < BEAM; b++) { w0[b] = 0.f; w1[b] = 0.f; }
        int j0 = tid, j1 = tid + 256;
        for (int s = 0; s < SLEN; ++s) {
            float c0 = (j0 < HD) ? context[s * HD + j0] : 0.f;
            float c1 = (j1 < HD) ? context[s * HD + j1] : 0.f;
#pragma unroll
            for (int b = 0; b < BEAM; b++) {
                float a = a_lds[b * SLEN + s];
                w0[b] += a * c0; w1[b] += a * c1;
            }
        }
#pragma unroll
        for (int b = 0; b < BEAM; b++) {
            if (j0 < HD) wctx_lds[b * HD + j0] = w0[b];
            if (j1 < HD) wctx_lds[b * HD + j1] = w1[b];
        }
    }
    __syncthreads();
    int j = blockIdx.x * 4 + wv;
    const float* w = attnW + (size_t)j * 1000;
    float acc[BEAM];
#pragma unroll
    for (int b = 0; b < BEAM; b++) acc[b] = 0.f;
    for (int ki = 0; ki < 16; ki++) {
        int k = ki * 64 + lane;
        if (k < 1000) {
            float wk = w[k];
#pragma unroll
            for (int b = 0; b < BEAM; b++) {
                float h = (k < HD) ? h2_lds[b * HD + k] : wctx_lds[b * HD + k - HD];
                acc[b] += wk * h;
            }
        }
    }
#pragma unroll
    for (int b = 0; b < BEAM; b++) {
        float v = acc[b];
        for (int o = 32; o; o >>= 1) v += __shfl_down(v, o);
        acc[b] = v;
    }
    if (lane == 0) {
#pragma unroll
        for (int b = 0; b < BEAM; b++) o_ws[b * HD + j] = tanhf(acc[b]);
    }
}

__global__ void k_logits_f(const float* __restrict__ outW, const float* __restrict__ outB,
                           const float* __restrict__ o_ws, float* __restrict__ logits,
                           double* __restrict__ partials) {
    __shared__ float o_lds[BEAM * HD];
    __shared__ double ered[4][BEAM];
    int tid = threadIdx.x;
    for (int idx = tid; idx < BEAM * HD; idx += 256) o_lds[idx] = o_ws[idx];
    __syncthreads();
    int wv = tid >> 6, lane = tid & 63;
    int w = blockIdx.x * 4 + wv;
    double esum = 0.0;
    for (int pi = 0; pi < 16; pi++) {
        int p = w * 16 + pi;
        if (p >= PV) break;
        const float* wr = outW + (size_t)p * HD;
        float acc[BEAM];
#pragma unroll
        for (int b = 0; b < BEAM; b++) acc[b] = 0.f;
        for (int ki = 0; ki < 8; ki++) {
            int k = ki * 64 + lane;
            if (k < HD) {
                float x = wr[k];
#pragma unroll
                for (int b = 0; b < BEAM; b++) acc[b] += x * o_lds[b * HD + k];
            }
        }
#pragma unroll
        for (int b = 0; b < BEAM; b++)
            for (int o = 32; o; o >>= 1) acc[b] += __shfl_xor(acc[b], o);
        if (lane < BEAM) {
            float lg = 0.f;
#pragma unroll
            for (int b = 0; b < BEAM; b++) if (lane == b) lg = acc[b];
            lg += outB[p];
            logits[(size_t)lane * PV + p] = lg;
            esum += exp((double)lg);
        }
    }
    if (lane < BEAM) ered[wv][lane] = esum;
    __syncthreads();
    if (tid < BEAM) partials[blockIdx.x * BEAM + tid] =
        ered[0][tid] + ered[1][tid] + ered[2][tid] + ered[3][tid];
}

__global__ __launch_bounds__(256) void k_topk_row(const float* __restrict__ logits,
                                                  u64* __restrict__ cands) {
    const int CH = 1563;
    int r = blockIdx.x >> 5, ci = blockIdx.x & 31;
    int base = ci * CH;
    int tid = threadIdx.x;
    int wv = tid >> 6, lane = tid & 63;
    u64 key[7];
#pragma unroll
    for (int e = 0; e < 7; e++) {
        int p = base + e * 256 + tid;
        key[e] = 0ull;
        if (p < base + CH && p < PV) {
            float v = logits[(size_t)r * PV + p];
            key[e] = ((u64)fkey(v) << 32) | (unsigned)(~(unsigned)p);
        }
    }
    __shared__ u64 wred[4];
    __shared__ u64 winlds;
    for (int round = 0; round < BEAM; round++) {
        u64 mx = 0ull;
#pragma unroll
        for (int e = 0; e < 7; e++) if (key[e] > mx) mx = key[e];
        for (int o = 32; o; o >>= 1) {
            u64 other = __shfl_down(mx, o);
            if (other > mx) mx = other;
        }
        if (lane == 0) wred[wv] = mx;
        __syncthreads();
        if (tid == 0) {
            u64 wn = wred[0];
            for (int i = 1; i < 4; i++) if (wred[i] > wn) wn = wred[i];
            winlds = wn;
            cands[blockIdx.x * BEAM + round] = wn;
        }
        __syncthreads();
        u64 win = winlds;
#pragma unroll
        for (int e = 0; e < 7; e++) if (key[e] == win) key[e] = 0ull;
    }
}

__global__ __launch_bounds__(256) void k_merge(
        const double* __restrict__ partials, int npart,
        const u64* __restrict__ cands,
        double* __restrict__ scores, int* __restrict__ tokens,
        const float* __restrict__ h2_ws, const float* __restrict__ c2_ws,
        float* __restrict__ h_ws, float* __restrict__ c_ws,
        int* __restrict__ prevKs, int* __restrict__ nextYs, int t) {
    __shared__ double wredd[4];
    __shared__ double lse_lds[BEAM];
    __shared__ double sc_lds[BEAM];
    __shared__ double bwv[4];
    __shared__ unsigned bwf[4];
    __shared__ unsigned winf_s;
    __shared__ int pk_lds[BEAM];
    __shared__ int ny_lds[BEAM];
    __shared__ double val_lds[BEAM];
    int tid = threadIdx.x;
    int wv = tid >> 6, lane = tid & 63;
    if (tid < BEAM) sc_lds[tid] = scores[tid];
    for (int b = 0; b < BEAM; b++) {
        double s = 0.0;
        for (int j = tid; j < npart; j += 256) s += partials[j * BEAM + b];
        for (int o = 32; o; o >>= 1) s += __shfl_down(s, o);
        if (lane == 0) wredd[wv] = s;
        __syncthreads();
        if (tid == 0) lse_lds[b] = log(wredd[0] + wredd[1] + wredd[2] + wredd[3]);
        __syncthreads();
    }
    double   cv[13];
    unsigned cf[13];
#pragma unroll
    for (int e = 0; e < 13; e++) {
        int c = e * 256 + tid;
        cv[e] = -1.0e308; cf[e] = 0xFFFFFFFFu;
        if (c < 3200) {
            u64 k0 = cands[c];
            if (k0) {
                int r = c / 320;
                float v = unfkey((unsigned)(k0 >> 32));
                unsigned p = ~((unsigned)k0);
                double v2;
                if (t == 0) v2 = (r == 0) ? ((double)v - lse_lds[0]) : (double)NEGF;
                else        v2 = ((double)v - lse_lds[r]) + sc_lds[r];
                cv[e] = v2;
                cf[e] = (unsigned)r * PV + p;
            }
        }
    }
    for (int round = 0; round < BEAM; round++) {
        double bv = -1.0e308; unsigned bf = 0xFFFFFFFFu;
#pragma unroll
        for (int e = 0; e < 13; e++) {
            if (cv[e] > bv || (cv[e] == bv && cf[e] < bf)) { bv = cv[e]; bf = cf[e]; }
        }
        for (int o = 32; o; o >>= 1) {
            double ov = __shfl_down(bv, o);
            unsigned of = __shfl_down(bf, o);
            if (ov > bv || (ov == bv && of < bf)) { bv = ov; bf = of; }
        }
        if (lane == 0) { bwv[wv] = bv; bwf[wv] = bf; }
        __syncthreads();
        if (tid == 0) {
            double xv = bwv[0]; unsigned xf = bwf[0];
            for (int i = 1; i < 4; i++) {
                if (bwv[i] > xv || (bwv[i] == xv && bwf[i] < xf)) { xv = bwv[i]; xf = bwf[i]; }
            }
            winf_s = xf;
            int pk = (int)(xf / PV);
            int ny = (int)(xf - (unsigned)pk * PV);
            pk_lds[round] = pk; ny_lds[round] = ny; val_lds[round] = xv;
        }
        __syncthreads();
        unsigned wff = winf_s;
#pragma unroll
        for (int e = 0; e < 13; e++) {
            if (cf[e] == wff) { cv[e] = -1.0e308; cf[e] = 0xFFFFFFFFu; }
        }
    }
    if (tid < BEAM) {
        scores[tid] = val_lds[tid];
        tokens[tid] = ny_lds[tid];
        prevKs[t * BEAM + tid] = pk_lds[tid];
        nextYs[t * BEAM + tid] = ny_lds[tid];
    }
    __syncthreads();
    for (int idx = tid; idx < BEAM * HD; idx += 256) {
        int i = idx / HD, j = idx - i * HD;
        h_ws[idx] = h2_ws[pk_lds[i] * HD + j];
        c_ws[idx] = c2_ws[pk_lds[i] * HD + j];
    }
}

__global__ void k_traceback(const int* __restrict__ prevKs, const int* __restrict__ nextYs,
                            int* __restrict__ out) {
    int k = threadIdx.x;
    if (k >= BEAM) return;
    int cur = k;
    for (int t = MAXLEN - 1; t >= 0; t--) {
        out[k * MAXLEN + t] = nextYs[t * BEAM + cur];
        cur = prevKs[t * BEAM + cur];
    }
}

extern "C" void kernel_launch(void* const* d_in, const int* in_sizes, int n_in,
                              void* d_out, int out_size, void* d_ws, size_t ws_size,
                              hipStream_t stream) {
    const int*   g_seq  = (const int*)  d_in[0];
    const float* encEmb = (const float*)d_in[1];
    const float* encWih = (const float*)d_in[2];
    const float* encWhh = (const float*)d_in[3];
    const float* encBih = (const float*)d_in[4];
    const float* encBhh = (const float*)d_in[5];
    const float* decEmb = (const float*)d_in[6];
    const float* decWih = (const float*)d_in[7];
    const float* decWhh = (const float*)d_in[8];
    const float* decBih = (const float*)d_in[9];
    const float* decBhh = (const float*)d_in[10];
    const float* attnW  = (const float*)d_in[11];
    const float* outW   = (const float*)d_in[12];
    const float* outB   = (const float*)d_in[13];

    float* ws = (float*)d_ws;
    float*  X     = ws + OFF_X;
    float*  cbuf  = ws + OFF_CBUF;
    float*  gbuf  = ws + OFF_GBUF;
    float*  ctx   = ws + OFF_CTX;
    float*  dh    = ws + OFF_DH;
    float*  dc    = ws + OFF_DC;
    float*  dg    = ws + OFF_DG;
    float*  h2    = ws + OFF_H2;
    float*  c2    = ws + OFF_C2;
    float*  o     = ws + OFF_O;
    double* scb   = (double*)(ws + OFF_SCD);
    int*    tok   = (int*)(ws + OFF_TOK);
    int*    prevK = (int*)(ws + OFF_PREVK);
    int*    nextY = (int*)(ws + OFF_NEXTY);
    float*  outW4 = ws + OFF_OWT;

    bool bigws = (ws_size >= NEED_T_BYTES);

    k_prep<<<16000, 256, 0, stream>>>(g_seq, encEmb, encWih, encBih, encBhh, X, cbuf);
    if (bigws) k_transpose4<<<dim3(782, 8), 256, 0, stream>>>(outW, outW4);

    for (int t = 0; t <= SLEN; t++)
        k_enc<<<250, 256, 0, stream>>>(encWhh, X, gbuf, cbuf, ctx, dh, dc, scb, tok, t);

    if (bigws) {
        double* part = (double*)(ws + OFF_PARTD);
        u64*    cand = (u64*)(ws + OFF_CAND);
        for (int t = 0; t < MAXLEN; t++) {
            int m = t - 1;
            const double* sin = scb + ((m & 1) ? 10 : 0);
            double*       sout = scb + (((m + 1) & 1) ? 10 : 0);
            if (t == 0) { sin = scb; sout = scb + 10; }
            k_gates_m<<<125, 512, 0, stream>>>(decEmb, decWih, decWhh, decBih, decBhh,
                                               part, cand, sin, sout,
                                               h2, c2, dc, dh, prevK, nextY, dg, t);
            k_fused<<<NSTRIP, 1024, 0, stream>>>(dg, dc, ctx, attnW, h2, c2,
                                                 outW4, outB, cand, part);
        }
        int mf = MAXLEN - 1;
        k_final<<<1, 512, 0, stream>>>(part, cand, scb + ((mf & 1) ? 10 : 0),
                                       prevK, nextY, (int*)d_out);
    } else {
        // R4-validated fallback (row-major out_W)
        double* part  = (double*)(ws + OFF_PARTF);
        u64*    cand  = (u64*)(ws + OFF_CANDF);
        float*  logits = ws + OFF_LOG;
        const int npart = 782;
        for (int t = 0; t < MAXLEN; t++) {
            k_gates<<<125, 1024, 0, stream>>>(decEmb, decWih, decWhh, decBih, decBhh, tok, dh, dg);
            k_attn_oproj<<<125, 256, 0, stream>>>(dg, dc, ctx, attnW, h2, c2, o);
            k_logits_f<<<782, 256, 0, stream>>>(outW, outB, o, logits, part);
            k_topk_row<<<320, 256, 0, stream>>>(logits, cand);
            k_merge<<<1, 256, 0, stream>>>(part, npart, cand, scb, tok, h2, c2, dh, dc, prevK, nextY, t);
        }
        k_traceback<<<1, 64, 0, stream>>>(prevK, nextY, (int*)d_out);
    }
}

// Round 14
// 3994.389 us; speedup vs baseline: 2.1566x; 2.1566x over previous
//
#include <hip/hip_runtime.h>
#include <math.h>

#define BEAM   10
#define MAXLEN 32
#define SLEN   32
#define HD     500
#define ED     500
#define G4     2000
#define PV     50000
#define NEGF   (-1e30f)
#define NEGD   (-1.0e30)

#define NSTRIP 196               // logits strip blocks (196*256 >= 50000)
#define CPR    (NSTRIP * BEAM)   // 1960 candidates per row

typedef unsigned long long u64;

// ---------------- ws layout (float element offsets) ----------------
#define OFF_X      0
#define OFF_CBUF   64000
#define OFF_GBUF   65000
#define OFF_CTX    69000
#define OFF_DH     85000
#define OFF_DC     90000
#define OFF_DG     95000
#define OFF_H2     115000
#define OFF_C2     120000
#define OFF_O      125000
#define OFF_SCD    135000   // double[20] score ping-pong
#define OFF_TOK    135040
#define OFF_PREVK  135060
#define OFF_NEXTY  135380
// fallback-path regions (R4 layout)
#define OFF_PARTF  136000   // double[7820]
#define OFF_CANDF  152000   // u64[3200]
#define OFF_LOG    160000   // fallback logits buffer
// new-path regions (inside fallback LOG region; paths exclusive)
#define OFF_PARTD  160284   // double[1960]
#define OFF_CAND   165604   // u64[19600]
#define OFF_OWT    660000   // float4-blocked transposed out_W (100 MB)
#define NEED_T_BYTES ((size_t)(OFF_OWT + (size_t)HD * PV) * 4)

__device__ __forceinline__ float sigf(float x) { return 1.f / (1.f + expf(-x)); }

__device__ __forceinline__ unsigned fkey(float f) {
    unsigned u = __float_as_uint(f);
    return (u & 0x80000000u) ? ~u : (u | 0x80000000u);
}
__device__ __forceinline__ float unfkey(unsigned k) {
    unsigned u = (k & 0x80000000u) ? (k & 0x7fffffffu) : ~k;
    return __uint_as_float(u);
}

// ---------------- fused prep + out_W transpose ----------------
// blocks [0,16000): X projection (identical math to validated k_prep)
// blocks [16000,16000+6256): blocked transpose (identical to validated k_transpose4)
__global__ void k_prep_tr(const int* __restrict__ g_seq, const float* __restrict__ enc_emb,
                          const float* __restrict__ Wih, const float* __restrict__ bih,
                          const float* __restrict__ bhh, float* __restrict__ X,
                          float* __restrict__ cbuf0,
                          const float* __restrict__ outW, float* __restrict__ outW4) {
    __shared__ float t_lds[64][65];
    int tid = threadIdx.x;
    if (blockIdx.x < 16000) {
        if (blockIdx.x == 0) {
            for (int j = tid; j < HD; j += 256) cbuf0[j] = 0.f;
        }
        int wv = (blockIdx.x * 256 + tid) >> 6;
        int lane = tid & 63;
        if (wv >= SLEN * G4) return;
        int t = wv / G4, r = wv - t * G4;
        const float* emb = enc_emb + (size_t)g_seq[t] * ED;
        const float* w = Wih + (size_t)r * ED;
        float acc = 0.f;
        for (int ki = 0; ki < 8; ki++) { int k = ki * 64 + lane; if (k < ED) acc += emb[k] * w[k]; }
        for (int o = 32; o; o >>= 1) acc += __shfl_down(acc, o);
        if (lane == 0) X[t * G4 + r] = acc + bih[r] + bhh[r];
    } else {
        int bid2 = blockIdx.x - 16000;
        int pbase = (bid2 % 782) * 64, kbase = (bid2 / 782) * 64;
        for (int e = 0; e < 16; e++) {
            int idx = e * 256 + tid; int pl = idx >> 6, kl = idx & 63;
            int pp = pbase + pl, kk = kbase + kl;
            t_lds[pl][kl] = (pp < PV && kk < HD) ? outW[(size_t)pp * HD + kk] : 0.f;
        }
        __syncthreads();
        for (int e = 0; e < 4; e++) {
            int idx = e * 256 + tid;
            int pl = idx & 63, kb = idx >> 6;
            int pp = pbase + pl;
            int kglob = kbase + kb * 4;
            if (pp < PV && kglob < HD) {
                float4 v;
                v.x = t_lds[pl][kb * 4 + 0];
                v.y = t_lds[pl][kb * 4 + 1];
                v.z = t_lds[pl][kb * 4 + 2];
                v.w = t_lds[pl][kb * 4 + 3];
                *(float4*)(outW4 + ((size_t)(kbase / 4 + kb) * PV + pp) * 4) = v;
            }
        }
    }
}

// ---------------- encoder step (R4-validated) ----------------
__global__ void k_enc(const float* __restrict__ Whh, const float* __restrict__ X,
                      float* __restrict__ gbuf, float* __restrict__ cbuf,
                      float* __restrict__ context, float* __restrict__ dec_h,
                      float* __restrict__ dec_c, double* __restrict__ scores,
                      int* __restrict__ tokens, int t) {
    __shared__ float h_lds[HD];
    const float* gprev = gbuf + ((t + 1) & 1) * G4;
    float*       gcur  = gbuf + (t & 1) * G4;
    const float* cprev = cbuf + ((t + 1) & 1) * HD;
    float*       ccur  = cbuf + (t & 1) * HD;
    int tid = threadIdx.x;
    if (t > 0) {
        for (int j = tid; j < HD; j += 256) {
            float gi = gprev[j], gf = gprev[HD + j], gg = gprev[2 * HD + j], go = gprev[3 * HD + j];
            float c = sigf(gf) * cprev[j] + sigf(gi) * tanhf(gg);
            float h = sigf(go) * tanhf(c);
            h_lds[j] = h;
            if (blockIdx.x == 0) {
                ccur[j] = c;
                context[(t - 1) * HD + j] = h;
                if (t == SLEN) {
                    for (int b = 0; b < BEAM; b++) { dec_h[b * HD + j] = h; dec_c[b * HD + j] = c; }
                }
            }
        }
    } else {
        for (int j = tid; j < HD; j += 256) h_lds[j] = 0.f;
    }
    if (t == SLEN && blockIdx.x == 0 && tid == 0) {
        for (int b = 0; b < BEAM; b++) scores[b] = 0.0;
        tokens[0] = 2; for (int b = 1; b < BEAM; b++) tokens[b] = 1;
    }
    __syncthreads();
    if (t < SLEN) {
        int wv = blockIdx.x * 4 + (tid >> 6), lane = tid & 63;
        for (int r = wv; r < G4; r += 1000) {
            const float* w = Whh + (size_t)r * HD;
            float acc = 0.f;
            for (int ki = 0; ki < 8; ki++) { int k = ki * 64 + lane; if (k < HD) acc += h_lds[k] * w[k]; }
            for (int o = 32; o; o >>= 1) acc += __shfl_down(acc, o);
            if (lane == 0) gcur[r] = X[t * G4 + r] + acc;
        }
    }
}

// ================= redundant merge (device fn, 512 threads) =================
struct MrgSm {
    double lse[BEAM]; double scl[BEAM];
    u64 rc[BEAM * BEAM];
    double gbv[8]; unsigned gbf[8]; unsigned winf;
    int pk[BEAM]; int ny[BEAM]; double val[BEAM];
};

__device__ __forceinline__ void do_merge(MrgSm* M, const double* __restrict__ part,
                                         const u64* __restrict__ cand,
                                         const double* __restrict__ sc_in,
                                         int m, int tid) {
    int wv = tid >> 6, lane = tid & 63;
    if (tid < BEAM) M->scl[tid] = sc_in[tid];
    // per-row lse (fp64)
    for (int r = wv; r < BEAM; r += 8) {
        double s = 0.0;
        for (int i = lane; i < NSTRIP; i += 64) s += part[r * NSTRIP + i];
        for (int o = 32; o; o >>= 1) s += __shfl_down(s, o);
        if (lane == 0) M->lse[r] = log(s);
    }
    // per-row top-10 over 1960 strip candidates; STATIC indexing (rule #20)
    for (int r = wv; r < BEAM; r += 8) {
        u64 kk[31];
#pragma unroll
        for (int e = 0; e < 31; e++) {
            int i = lane + e * 64;
            kk[e] = (i < CPR) ? cand[(size_t)r * CPR + i] : 0ull;
        }
        for (int round = 0; round < BEAM; ++round) {
            u64 mx = 0ull;
#pragma unroll
            for (int e = 0; e < 31; e++) if (kk[e] > mx) mx = kk[e];
            for (int o = 32; o; o >>= 1) { u64 t2 = __shfl_down(mx, o); if (t2 > mx) mx = t2; }
            u64 win = __shfl(mx, 0);
#pragma unroll
            for (int e = 0; e < 31; e++) if (kk[e] == win) kk[e] = 0ull;
            if (lane == 0) M->rc[r * BEAM + round] = win;
        }
    }
    __syncthreads();
    // global merge over 100 candidates (fp64 value, flat-index tiebreak)
    double cv = -1.0e308; unsigned cf = 0xFFFFFFFFu;
    if (tid < BEAM * BEAM) {
        u64 k0 = M->rc[tid];
        if (k0) {
            int r2 = tid / BEAM;
            float v = unfkey((unsigned)(k0 >> 32));
            unsigned p = ~((unsigned)k0);
            double v2;
            if (m == 0) v2 = (r2 == 0) ? ((double)v - M->lse[0]) : NEGD;
            else        v2 = ((double)v - M->lse[r2]) + M->scl[r2];
            cv = v2; cf = (unsigned)r2 * PV + p;
        }
    }
    for (int round = 0; round < BEAM; ++round) {
        double bv = cv; unsigned bf = cf;
        for (int o = 32; o; o >>= 1) {
            double ov = __shfl_down(bv, o);
            unsigned of = __shfl_down(bf, o);
            if (ov > bv || (ov == bv && of < bf)) { bv = ov; bf = of; }
        }
        if (lane == 0) { M->gbv[wv] = bv; M->gbf[wv] = bf; }
        __syncthreads();
        if (tid == 0) {
            double xv = M->gbv[0]; unsigned xf = M->gbf[0];
            for (int i = 1; i < 8; i++) {
                if (M->gbv[i] > xv || (M->gbv[i] == xv && M->gbf[i] < xf)) { xv = M->gbv[i]; xf = M->gbf[i]; }
            }
            M->winf = xf;
            int pk = (int)(xf / PV);
            int ny = (int)(xf - (unsigned)pk * PV);
            M->pk[round] = pk; M->ny[round] = ny; M->val[round] = xv;
        }
        __syncthreads();
        if (cf == M->winf) { cv = -1.0e308; cf = 0xFFFFFFFFu; }
        __syncthreads();
    }
}

// ================= fused merge(t-1) + gates (125 x 512) =================
// At t==0 additionally performs the encoder's final pointwise step
// (element-wise formula identical to k_enc's t==SLEN branch).
__global__ __launch_bounds__(512) void k_gates_m(
        const float* __restrict__ decEmb, const float* __restrict__ Wih,
        const float* __restrict__ Whh, const float* __restrict__ bih,
        const float* __restrict__ bhh,
        const double* __restrict__ part, const u64* __restrict__ cand,
        const double* __restrict__ sc_in, double* __restrict__ sc_out,
        const float* __restrict__ h2w, const float* __restrict__ c2w,
        float* __restrict__ dc,
        const float* __restrict__ gbuf, const float* __restrict__ cbuf,
        float* __restrict__ ctx,
        int* __restrict__ prevK, int* __restrict__ nextY,
        float* __restrict__ gates, int t) {
    __shared__ float e_lds[BEAM * ED];
    __shared__ float h_lds[BEAM * HD];
    __shared__ MrgSm M;
    int tid = threadIdx.x, bid = blockIdx.x;
    int wv = tid >> 6, lane = tid & 63;

    if (t > 0) {
        int m = t - 1;
        do_merge(&M, part, cand, sc_in, m, tid);
        if (tid < BEAM && bid == 0) {
            sc_out[tid] = M.val[tid];
            prevK[m * BEAM + tid] = M.pk[tid];
            nextY[m * BEAM + tid] = M.ny[tid];
        }
        __syncthreads();
        for (int idx = tid; idx < BEAM * HD; idx += 512) {
            int b = idx / HD, j = idx - b * HD;
            h_lds[idx] = h2w[M.pk[b] * HD + j];
            e_lds[idx] = decEmb[(size_t)M.ny[b] * ED + j];
            if (bid == 0) dc[idx] = c2w[M.pk[b] * HD + j];
        }
    } else {
        // encoder final pointwise: gates(31) at gbuf+G4, c31 at cbuf+HD
        const float* gb = gbuf + G4;
        const float* cp = cbuf + HD;
        for (int j = tid; j < HD; j += 512) {
            float gi = gb[j], gf = gb[HD + j], gg = gb[2 * HD + j], go = gb[3 * HD + j];
            float c = sigf(gf) * cp[j] + sigf(gi) * tanhf(gg);
            float h = sigf(go) * tanhf(c);
            if (bid == 0) {
                ctx[(SLEN - 1) * HD + j] = h;
                for (int b = 0; b < BEAM; b++) dc[b * HD + j] = c;
            }
            for (int b = 0; b < BEAM; b++) h_lds[b * HD + j] = h;
        }
        for (int idx = tid; idx < BEAM * ED; idx += 512) {
            int b = idx / ED, j = idx - b * ED;
            int tk = (b == 0) ? 2 : 1;
            e_lds[idx] = decEmb[(size_t)tk * ED + j];
        }
    }
    __syncthreads();

    // gates: 16 rows/block, 2 rows/wave (per-row math identical to R4 k_gates)
    for (int rr = 0; rr < 2; ++rr) {
        int r = bid * 16 + wv * 2 + rr;
        const float* wi = Wih + (size_t)r * ED;
        const float* wh = Whh + (size_t)r * HD;
        float acc[BEAM];
#pragma unroll
        for (int b = 0; b < BEAM; b++) acc[b] = 0.f;
        for (int ki = 0; ki < 8; ki++) {
            int k = ki * 64 + lane;
            if (k < ED) {
                float w = wi[k];
#pragma unroll
                for (int b = 0; b < BEAM; b++) acc[b] += w * e_lds[b * ED + k];
            }
        }
        for (int ki = 0; ki < 8; ki++) {
            int k = ki * 64 + lane;
            if (k < HD) {
                float w = wh[k];
#pragma unroll
                for (int b = 0; b < BEAM; b++) acc[b] += w * h_lds[b * HD + k];
            }
        }
#pragma unroll
        for (int b = 0; b < BEAM; b++) {
            float v = acc[b];
            for (int o = 32; o; o >>= 1) v += __shfl_down(v, o);
            acc[b] = v;
        }
        if (lane == 0) {
            float bb = bih[r] + bhh[r];
#pragma unroll
            for (int b = 0; b < BEAM; b++) gates[b * G4 + r] = acc[b] + bb;
        }
    }
}

// ---------------- attn + oproj (125 x 256, R4-validated) ----------------
__global__ __launch_bounds__(256) void k_attn_oproj(
        const float* __restrict__ gates, const float* __restrict__ c_ws,
        const float* __restrict__ context, const float* __restrict__ attnW,
        float* __restrict__ h2_ws, float* __restrict__ c2_ws, float* __restrict__ o_ws) {
    __shared__ float h2_lds[BEAM * HD];
    __shared__ float wctx_lds[BEAM * HD];
    __shared__ float s_lds[BEAM * SLEN];
    __shared__ float a_lds[BEAM * SLEN];
    int tid = threadIdx.x;
    int wv = tid >> 6, lane = tid & 63;
    for (int idx = tid; idx < BEAM * HD; idx += 256) {
        int b = idx / HD, j = idx - b * HD;
        float gi = gates[b * G4 + j], gf = gates[b * G4 + HD + j];
        float gg = gates[b * G4 + 2 * HD + j], go = gates[b * G4 + 3 * HD + j];
        float c = sigf(gf) * c_ws[idx] + sigf(gi) * tanhf(gg);
        float h2 = sigf(go) * tanhf(c);
        h2_lds[idx] = h2;
        if (blockIdx.x == 0) { c2_ws[idx] = c; h2_ws[idx] = h2; }
    }
    __syncthreads();
    for (int si = 0; si < 8; ++si) {
        int s = wv + 4 * si;
        float acc[BEAM];
#pragma unroll
        for (int b = 0; b < BEAM; b++) acc[b] = 0.f;
        for (int ki = 0; ki < 8; ki++) {
            int k = ki * 64 + lane;
            if (k < HD) {
                float c = context[s * HD + k];
#pragma unroll
                for (int b = 0; b < BEAM; b++) acc[b] += c * h2_lds[b * HD + k];
            }
        }
#pragma unroll
        for (int b = 0; b < BEAM; b++) {
            float v = acc[b];
            for (int o = 32; o; o >>= 1) v += __shfl_down(v, o);
            if (lane == 0) s_lds[b * SLEN + s] = v;
        }
    }
    __syncthreads();
    if (wv == 0) {
        for (int b = 0; b < BEAM; ++b) {
            float v = (lane < SLEN) ? s_lds[b * SLEN + lane] : -INFINITY;
            float m = v;
            for (int o = 32; o; o >>= 1) m = fmaxf(m, __shfl_xor(m, o));
            float e = (lane < SLEN) ? expf(v - m) : 0.f;
            float sum = e;
            for (int o = 32; o; o >>= 1) sum += __shfl_xor(sum, o);
            if (lane < SLEN) a_lds[b * SLEN + lane] = e / sum;
        }
    }
    __syncthreads();
    {
        float w0[BEAM], w1[BEAM];
#pragma unroll
        for (int b = 0; b < BEAM; b++) { w0[b] = 0.f; w1[b] = 0.f; }
        int j0 = tid, j1 = tid + 256;
        for (int s = 0; s < SLEN; ++s) {
            float c0 = (j0 < HD) ? context[s * HD + j0] : 0.f;
            float c1 = (j1 < HD) ? context[s * HD + j1] : 0.f;
#pragma unroll
            for (int b = 0; b < BEAM; b++) {
                float a = a_lds[b * SLEN + s];
                w0[b] += a * c0; w1[b] += a * c1;
            }
        }
#pragma unroll
        for (int b = 0; b < BEAM; b++) {
            if (j0 < HD) wctx_lds[b * HD + j0] = w0[b];
            if (j1 < HD) wctx_lds[b * HD + j1] = w1[b];
        }
    }
    __syncthreads();
    int j = blockIdx.x * 4 + wv;
    const float* w = attnW + (size_t)j * 1000;
    float acc[BEAM];
#pragma unroll
    for (int b = 0; b < BEAM; b++) acc[b] = 0.f;
    for (int ki = 0; ki < 16; ki++) {
        int k = ki * 64 + lane;
        if (k < 1000) {
            float wk = w[k];
#pragma unroll
            for (int b = 0; b < BEAM; b++) {
                float h = (k < HD) ? h2_lds[b * HD + k] : wctx_lds[b * HD + k - HD];
                acc[b] += wk * h;
            }
        }
    }
#pragma unroll
    for (int b = 0; b < BEAM; b++) {
        float v = acc[b];
        for (int o = 32; o; o >>= 1) v += __shfl_down(v, o);
        acc[b] = v;
    }
    if (lane == 0) {
#pragma unroll
        for (int b = 0; b < BEAM; b++) o_ws[b * HD + j] = tanhf(acc[b]);
    }
}

// ---------------- fused logits + strip top-10 + fp64 sumexp (196 x 1024) ----------------
__global__ __launch_bounds__(1024) void k_logits_topk(
        const float* __restrict__ outW4, const float* __restrict__ outB,
        const float* __restrict__ o_ws, u64* __restrict__ cand,
        double* __restrict__ part) {
    __shared__ __align__(16) char sm[61440];
    float4* o4 = (float4*)sm;                 // [0, 20480)
    float*  pt = (float*)(sm + 20480);        // [20480, 61440)
    int tid = threadIdx.x, bid = blockIdx.x;
    int lane = tid & 63;
    int col = tid & 255, kc = tid >> 8;
    for (int idx = tid; idx < BEAM * 125; idx += 1024) {
        int b = idx / 125, kb = idx - b * 125;
        o4[idx] = *(const float4*)(o_ws + b * HD + kb * 4);
    }
    __syncthreads();
    int p = bid * 256 + col;
    bool valid = (p < PV);
    int pc = valid ? p : (PV - 1);
    {
        float acc[BEAM];
#pragma unroll
        for (int b = 0; b < BEAM; b++) acc[b] = 0.f;
        int kb0 = kc * 32, kb1 = (kc == 3) ? 125 : (kb0 + 32);
        const float4* wp = (const float4*)outW4;
        for (int kb = kb0; kb < kb1; ++kb) {
            float4 w = wp[(size_t)kb * PV + pc];
#pragma unroll
            for (int b = 0; b < BEAM; b++) {
                float4 o = o4[b * 125 + kb];
                acc[b] += w.x * o.x + w.y * o.y + w.z * o.z + w.w * o.w;
            }
        }
#pragma unroll
        for (int b = 0; b < BEAM; b++) pt[(kc * 256 + col) * BEAM + b] = acc[b];
    }
    __syncthreads();
    float lg[BEAM];
    if (tid < 256) {
        float ob = outB[pc];
#pragma unroll
        for (int b = 0; b < BEAM; b++)
            lg[b] = pt[(0 * 256 + tid) * BEAM + b] + pt[(1 * 256 + tid) * BEAM + b]
                  + pt[(2 * 256 + tid) * BEAM + b] + pt[(3 * 256 + tid) * BEAM + b] + ob;
    }
    __syncthreads();
    double* pd = (double*)sm;            // [0,20480)
    u64*    kl = (u64*)(sm + 20480);     // [20480,40960)
    if (tid < 256) {
#pragma unroll
        for (int b = 0; b < BEAM; b++) {
            pd[b * 256 + tid] = valid ? exp((double)lg[b]) : 0.0;
            kl[b * 256 + tid] = valid ? (((u64)fkey(lg[b]) << 32) | (unsigned)(~(unsigned)p)) : 0ull;
        }
    }
    __syncthreads();
    int wv = tid >> 6;
    if (wv < BEAM) {
        int r = wv;
        double s = pd[r * 256 + lane] + pd[r * 256 + 64 + lane]
                 + pd[r * 256 + 128 + lane] + pd[r * 256 + 192 + lane];
        for (int o = 32; o; o >>= 1) s += __shfl_down(s, o);
        if (lane == 0) part[r * NSTRIP + bid] = s;
        u64 kk[4];
#pragma unroll
        for (int j = 0; j < 4; j++) kk[j] = kl[r * 256 + j * 64 + lane];
        for (int round = 0; round < BEAM; round++) {
            u64 m = kk[0];
            if (kk[1] > m) m = kk[1];
            if (kk[2] > m) m = kk[2];
            if (kk[3] > m) m = kk[3];
            for (int o = 32; o; o >>= 1) {
                u64 t2 = __shfl_down(m, o);
                if (t2 > m) m = t2;
            }
            u64 win = __shfl(m, 0);
#pragma unroll
            for (int j = 0; j < 4; j++) if (kk[j] == win) kk[j] = 0ull;
            if (lane == 0) cand[(size_t)r * CPR + bid * 10 + round] = win;
        }
    }
}

// ---------------- final merge(31) + traceback (1 x 512) ----------------
__global__ __launch_bounds__(512) void k_final(
        const double* __restrict__ part, const u64* __restrict__ cand,
        const double* __restrict__ sc_in,
        int* __restrict__ prevK, int* __restrict__ nextY, int* __restrict__ out) {
    __shared__ MrgSm M;
    int tid = threadIdx.x;
    do_merge(&M, part, cand, sc_in, MAXLEN - 1, tid);
    if (tid < BEAM) {
        prevK[(MAXLEN - 1) * BEAM + tid] = M.pk[tid];
        nextY[(MAXLEN - 1) * BEAM + tid] = M.ny[tid];
    }
    __syncthreads();
    if (tid < BEAM) {
        int cur = tid;
        for (int tt = MAXLEN - 1; tt >= 0; tt--) {
            out[tid * MAXLEN + tt] = nextY[tt * BEAM + cur];
            cur = prevK[tt * BEAM + cur];
        }
    }
}

// ======================================================================
// R4 fallback kernels (used only when ws is too small for transposed W)
// ======================================================================
__global__ __launch_bounds__(1024) void k_gates(
        const float* __restrict__ dec_emb, const float* __restrict__ Wih,
        const float* __restrict__ Whh, const float* __restrict__ bih,
        const float* __restrict__ bhh, const int* __restrict__ tokens,
        const float* __restrict__ h_ws, float* __restrict__ gates) {
    __shared__ float e_lds[BEAM * ED];
    __shared__ float h_lds[BEAM * HD];
    int tid = threadIdx.x;
    for (int idx = tid; idx < BEAM * ED; idx += 1024) {
        int b = idx / ED, k = idx - b * ED;
        e_lds[idx] = dec_emb[(size_t)tokens[b] * ED + k];
        h_lds[idx] = h_ws[idx];
    }
    __syncthreads();
    int wv = tid >> 6, lane = tid & 63;
    int r = blockIdx.x * 16 + wv;
    const float* wi = Wih + (size_t)r * ED;
    const float* wh = Whh + (size_t)r * HD;
    float acc[BEAM];
#pragma unroll
    for (int b = 0; b < BEAM; b++) acc[b] = 0.f;
    for (int ki = 0; ki < 8; ki++) {
        int k = ki * 64 + lane;
        if (k < ED) {
            float w = wi[k];
#pragma unroll
            for (int b = 0; b < BEAM; b++) acc[b] += w * e_lds[b * ED + k];
        }
    }
    for (int ki = 0; ki < 8; ki++) {
        int k = ki * 64 + lane;
        if (k < HD) {
            float w = wh[k];
#pragma unroll
            for (int b = 0; b < BEAM; b++) acc[b] += w * h_lds[b * HD + k];
        }
    }
#pragma unroll
    for (int b = 0; b < BEAM; b++) {
        float v = acc[b];
        for (int o = 32; o; o >>= 1) v += __shfl_down(v, o);
        acc[b] = v;
    }
    if (lane == 0) {
        float bb = bih[r] + bhh[r];
#pragma unroll
        for (int b = 0; b < BEAM; b++) gates[b * G4 + r] = acc[b] + bb;
    }
}

__global__ void k_logits_f(const float* __restrict__ outW, const float* __restrict__ outB,
                           const float* __restrict__ o_ws, float* __restrict__ logits,
                           double* __restrict__ partials) {
    __shared__ float o_lds[BEAM * HD];
    __shared__ double ered[4][BEAM];
    int tid = threadIdx.x;
    for (int idx = tid; idx < BEAM * HD; idx += 256) o_lds[idx] = o_ws[idx];
    __syncthreads();
    int wv = tid >> 6, lane = tid & 63;
    int w = blockIdx.x * 4 + wv;
    double esum = 0.0;
    for (int pi = 0; pi < 16; pi++) {
        int p = w * 16 + pi;
        if (p >= PV) break;
        const float* wr = outW + (size_t)p * HD;
        float acc[BEAM];
#pragma unroll
        for (int b = 0; b < BEAM; b++) acc[b] = 0.f;
        for (int ki = 0; ki < 8; ki++) {
            int k = ki * 64 + lane;
            if (k < HD) {
                float x = wr[k];
#pragma unroll
                for (int b = 0; b < BEAM; b++) acc[b] += x * o_lds[b * HD + k];
            }
        }
#pragma unroll
        for (int b = 0; b < BEAM; b++)
            for (int o = 32; o; o >>= 1) acc[b] += __shfl_xor(acc[b], o);
        if (lane < BEAM) {
            float lg = 0.f;
#pragma unroll
            for (int b = 0; b < BEAM; b++) if (lane == b) lg = acc[b];
            lg += outB[p];
            logits[(size_t)lane * PV + p] = lg;
            esum += exp((double)lg);
        }
    }
    if (lane < BEAM) ered[wv][lane] = esum;
    __syncthreads();
    if (tid < BEAM) partials[blockIdx.x * BEAM + tid] =
        ered[0][tid] + ered[1][tid] + ered[2][tid] + ered[3][tid];
}

__global__ __launch_bounds__(256) void k_topk_row(const float* __restrict__ logits,
                                                  u64* __restrict__ cands) {
    const int CH = 1563;
    int r = blockIdx.x >> 5, ci = blockIdx.x & 31;
    int base = ci * CH;
    int tid = threadIdx.x;
    int wv = tid >> 6, lane = tid & 63;
    u64 key[7];
#pragma unroll
    for (int e = 0; e < 7; e++) {
        int p = base + e * 256 + tid;
        key[e] = 0ull;
        if (p < base + CH && p < PV) {
            float v = logits[(size_t)r * PV + p];
            key[e] = ((u64)fkey(v) << 32) | (unsigned)(~(unsigned)p);
        }
    }
    __shared__ u64 wred[4];
    __shared__ u64 winlds;
    for (int round = 0; round < BEAM; round++) {
        u64 mx = 0ull;
#pragma unroll
        for (int e = 0; e < 7; e++) if (key[e] > mx) mx = key[e];
        for (int o = 32; o; o >>= 1) {
            u64 other = __shfl_down(mx, o);
            if (other > mx) mx = other;
        }
        if (lane == 0) wred[wv] = mx;
        __syncthreads();
        if (tid == 0) {
            u64 wn = wred[0];
            for (int i = 1; i < 4; i++) if (wred[i] > wn) wn = wred[i];
            winlds = wn;
            cands[blockIdx.x * BEAM + round] = wn;
        }
        __syncthreads();
        u64 win = winlds;
#pragma unroll
        for (int e = 0; e < 7; e++) if (key[e] == win) key[e] = 0ull;
    }
}

__global__ __launch_bounds__(256) void k_merge(
        const double* __restrict__ partials, int npart,
        const u64* __restrict__ cands,
        double* __restrict__ scores, int* __restrict__ tokens,
        const float* __restrict__ h2_ws, const float* __restrict__ c2_ws,
        float* __restrict__ h_ws, float* __restrict__ c_ws,
        int* __restrict__ prevKs, int* __restrict__ nextYs, int t) {
    __shared__ double wredd[4];
    __shared__ double lse_lds[BEAM];
    __shared__ double sc_lds[BEAM];
    __shared__ double bwv[4];
    __shared__ unsigned bwf[4];
    __shared__ unsigned winf_s;
    __shared__ int pk_lds[BEAM];
    __shared__ int ny_lds[BEAM];
    __shared__ double val_lds[BEAM];
    int tid = threadIdx.x;
    int wv = tid >> 6, lane = tid & 63;
    if (tid < BEAM) sc_lds[tid] = scores[tid];
    for (int b = 0; b < BEAM; b++) {
        double s = 0.0;
        for (int j = tid; j < npart; j += 256) s += partials[j * BEAM + b];
        for (int o = 32; o; o >>= 1) s += __shfl_down(s, o);
        if (lane == 0) wredd[wv] = s;
        __syncthreads();
        if (tid == 0) lse_lds[b] = log(wredd[0] + wredd[1] + wredd[2] + wredd[3]);
        __syncthreads();
    }
    double   cv[13];
    unsigned cf[13];
#pragma unroll
    for (int e = 0; e < 13; e++) {
        int c = e * 256 + tid;
        cv[e] = -1.0e308; cf[e] = 0xFFFFFFFFu;
        if (c < 3200) {
            u64 k0 = cands[c];
            if (k0) {
                int r = c / 320;
                float v = unfkey((unsigned)(k0 >> 32));
                unsigned p = ~((unsigned)k0);
                double v2;
                if (t == 0) v2 = (r == 0) ? ((double)v - lse_lds[0]) : (double)NEGF;
                else        v2 = ((double)v - lse_lds[r]) + sc_lds[r];
                cv[e] = v2;
                cf[e] = (unsigned)r * PV + p;
            }
        }
    }
    for (int round = 0; round < BEAM; round++) {
        double bv = -1.0e308; unsigned bf = 0xFFFFFFFFu;
#pragma unroll
        for (int e = 0; e < 13; e++) {
            if (cv[e] > bv || (cv[e] == bv && cf[e] < bf)) { bv = cv[e]; bf = cf[e]; }
        }
        for (int o = 32; o; o >>= 1) {
            double ov = __shfl_down(bv, o);
            unsigned of = __shfl_down(bf, o);
            if (ov > bv || (ov == bv && of < bf)) { bv = ov; bf = of; }
        }
        if (lane == 0) { bwv[wv] = bv; bwf[wv] = bf; }
        __syncthreads();
        if (tid == 0) {
            double xv = bwv[0]; unsigned xf = bwf[0];
            for (int i = 1; i < 4; i++) {
                if (bwv[i] > xv || (bwv[i] == xv && bwf[i] < xf)) { xv = bwv[i]; xf = bwf[i]; }
            }
            winf_s = xf;
            int pk = (int)(xf / PV);
            int ny = (int)(xf - (unsigned)pk * PV);
            pk_lds[round] = pk; ny_lds[round] = ny; val_lds[round] = xv;
        }
        __syncthreads();
        unsigned wff = winf_s;
#pragma unroll
        for (int e = 0; e < 13; e++) {
            if (cf[e] == wff) { cv[e] = -1.0e308; cf[e] = 0xFFFFFFFFu; }
        }
    }
    if (tid < BEAM) {
        scores[tid] = val_lds[tid];
        tokens[tid] = ny_lds[tid];
        prevKs[t * BEAM + tid] = pk_lds[tid];
        nextYs[t * BEAM + tid] = ny_lds[tid];
    }
    __syncthreads();
    for (int idx = tid; idx < BEAM * HD; idx += 256) {
        int i = idx / HD, j = idx - i * HD;
        h_ws[idx] = h2_ws[pk_lds[i] * HD + j];
        c_ws[idx] = c2_ws[pk_lds[i] * HD + j];
    }
}

__global__ void k_traceback(const int* __restrict__ prevKs, const int* __restrict__ nextYs,
                            int* __restrict__ out) {
    int k = threadIdx.x;
    if (k >= BEAM) return;
    int cur = k;
    for (int t = MAXLEN - 1; t >= 0; t--) {
        out[k * MAXLEN + t] = nextYs[t * BEAM + cur];
        cur = prevKs[t * BEAM + cur];
    }
}

extern "C" void kernel_launch(void* const* d_in, const int* in_sizes, int n_in,
                              void* d_out, int out_size, void* d_ws, size_t ws_size,
                              hipStream_t stream) {
    const int*   g_seq  = (const int*)  d_in[0];
    const float* encEmb = (const float*)d_in[1];
    const float* encWih = (const float*)d_in[2];
    const float* encWhh = (const float*)d_in[3];
    const float* encBih = (const float*)d_in[4];
    const float* encBhh = (const float*)d_in[5];
    const float* decEmb = (const float*)d_in[6];
    const float* decWih = (const float*)d_in[7];
    const float* decWhh = (const float*)d_in[8];
    const float* decBih = (const float*)d_in[9];
    const float* decBhh = (const float*)d_in[10];
    const float* attnW  = (const float*)d_in[11];
    const float* outW   = (const float*)d_in[12];
    const float* outB   = (const float*)d_in[13];

    float* ws = (float*)d_ws;
    float*  X     = ws + OFF_X;
    float*  cbuf  = ws + OFF_CBUF;
    float*  gbuf  = ws + OFF_GBUF;
    float*  ctx   = ws + OFF_CTX;
    float*  dh    = ws + OFF_DH;
    float*  dc    = ws + OFF_DC;
    float*  dg    = ws + OFF_DG;
    float*  h2    = ws + OFF_H2;
    float*  c2    = ws + OFF_C2;
    float*  o     = ws + OFF_O;
    double* scb   = (double*)(ws + OFF_SCD);
    int*    tok   = (int*)(ws + OFF_TOK);
    int*    prevK = (int*)(ws + OFF_PREVK);
    int*    nextY = (int*)(ws + OFF_NEXTY);
    float*  outW4 = ws + OFF_OWT;

    bool bigws = (ws_size >= NEED_T_BYTES);

    // fused prep + transpose (transpose blocks only when bigws)
    int prep_grid = bigws ? (16000 + 782 * 8) : 16000;
    k_prep_tr<<<prep_grid, 256, 0, stream>>>(g_seq, encEmb, encWih, encBih, encBhh,
                                             X, cbuf, outW, outW4);

    if (bigws) {
        // encoder: 32 launches (t=0..31); final pointwise folded into k_gates_m(t=0)
        for (int t = 0; t < SLEN; t++)
            k_enc<<<250, 256, 0, stream>>>(encWhh, X, gbuf, cbuf, ctx, dh, dc, scb, tok, t);

        double* part = (double*)(ws + OFF_PARTD);
        u64*    cand = (u64*)(ws + OFF_CAND);
        for (int t = 0; t < MAXLEN; t++) {
            int m = t - 1;
            const double* sin = scb + ((m & 1) ? 10 : 0);
            double*       sout = scb + (((m + 1) & 1) ? 10 : 0);
            if (t == 0) { sin = scb; sout = scb + 10; }
            k_gates_m<<<125, 512, 0, stream>>>(decEmb, decWih, decWhh, decBih, decBhh,
                                               part, cand, sin, sout,
                                               h2, c2, dc, gbuf, cbuf, ctx,
                                               prevK, nextY, dg, t);
            k_attn_oproj<<<125, 256, 0, stream>>>(dg, dc, ctx, attnW, h2, c2, o);
            k_logits_topk<<<NSTRIP, 1024, 0, stream>>>(outW4, outB, o, cand, part);
        }
        int mf = MAXLEN - 1;
        k_final<<<1, 512, 0, stream>>>(part, cand, scb + ((mf & 1) ? 10 : 0),
                                       prevK, nextY, (int*)d_out);
    } else {
        // R4-validated fallback (row-major out_W); encoder runs t=0..SLEN
        for (int t = 0; t <= SLEN; t++)
            k_enc<<<250, 256, 0, stream>>>(encWhh, X, gbuf, cbuf, ctx, dh, dc, scb, tok, t);
        double* part  = (double*)(ws + OFF_PARTF);
        u64*    cand  = (u64*)(ws + OFF_CANDF);
        float*  logits = ws + OFF_LOG;
        const int npart = 782;
        for (int t = 0; t < MAXLEN; t++) {
            k_gates<<<125, 1024, 0, stream>>>(decEmb, decWih, decWhh, decBih, decBhh, tok, dh, dg);
            k_attn_oproj<<<125, 256, 0, stream>>>(dg, dc, ctx, attnW, h2, c2, o);
            k_logits_f<<<782, 256, 0, stream>>>(outW, outB, o, logits, part);
            k_topk_row<<<320, 256, 0, stream>>>(logits, cand);
            k_merge<<<1, 256, 0, stream>>>(part, npart, cand, scb, tok, h2, c2, dh, dc, prevK, nextY, t);
        }
        k_traceback<<<1, 64, 0, stream>>>(prevK, nextY, (int*)d_out);
    }
}